// Round 14
// baseline (5548.439 us; speedup 1.0000x reference)
//
#include <hip/hip_runtime.h>
#include <hip/hip_bf16.h>

// Model dims: Tx=512 V=100 D=64 DM=512 NH=8 DFF=2048 NL=2 H=256 DATT=128 FCH=256 OUT=2

typedef __attribute__((ext_vector_type(8))) short short8;
typedef __attribute__((ext_vector_type(4))) float f32x4;

__device__ __forceinline__ int jglob_of(int e0, int jl) { return ((jl >> 4) << 8) + e0 + (jl & 15); }
__device__ __forceinline__ float blo(unsigned u) { return __uint_as_float(u << 16); }
__device__ __forceinline__ float bhi(unsigned u) { return __uint_as_float(u & 0xffff0000u); }
__device__ __forceinline__ short f2bs(float x) {
  union { __hip_bfloat16 h; short s; } u; u.h = __float2bfloat16(x); return u.s;
}
__device__ __forceinline__ float tanhf_fast(float x) {
  float e = __expf(2.f * x);
  return 1.f - 2.f * __builtin_amdgcn_rcpf(e + 1.f);
}

#define GLL16(GSRC, LDST) \
  __builtin_amdgcn_global_load_lds( \
      (const __attribute__((address_space(1))) unsigned int*)(GSRC), \
      (__attribute__((address_space(3))) unsigned int*)(LDST), 16, 0, 0)

// ===================== fused prologue: 6 weight converts + PE table =====================
// dst pool layout (shorts): in_wb[0,1572864) out_wb[,2097152) ff1[,4194304)
// ff2[,6291456) att1c[,6356992) wih[,6881280)
__global__ __launch_bounds__(256) void prep_kernel(
    const float* __restrict__ in_w, const float* __restrict__ out_w,
    const float* __restrict__ ff1_w, const float* __restrict__ ff2_w,
    const float* __restrict__ att1_w, const float* __restrict__ wih,
    __hip_bfloat16* __restrict__ dst, float* __restrict__ pe)
{
  int i = blockIdx.x * 256 + threadIdx.x;
  if (i < 6881280) {
    const float* s; long off;
    if (i < 1572864)      { s = in_w;  off = i; }
    else if (i < 2097152) { s = out_w; off = i - 1572864; }
    else if (i < 4194304) { s = ff1_w; off = i - 2097152; }
    else if (i < 6291456) { s = ff2_w; off = i - 4194304; }
    else if (i < 6356992) { int k = i - 6291456; s = att1_w; off = (long)(k >> 9) * 768 + (k & 511); }
    else                  { s = wih;   off = i - 6356992; }
    dst[i] = __float2bfloat16(s[off]);
  } else if (i < 6881280 + 51200) {
    int idx = i - 6881280;
    int v = idx >> 9, n = idx & 511;
    float d = expf(-(float)(n & ~1) * (9.2103403719761836f / 512.0f));
    float ang = (float)v * d;
    pe[idx] = (n & 1) ? cosf(ang) : sinf(ang);
  }
}

// ===================== bf16-input MFMA GEMM (m97-style) =====================
__global__ __launch_bounds__(256) void gemm_bf16(
    const __hip_bfloat16* __restrict__ A, long aBase, int aDiv, long aSA, long aSB,
    const __hip_bfloat16* __restrict__ W, int ldw,
    const float* __restrict__ bias,
    float* __restrict__ outF, __hip_bfloat16* __restrict__ outB,
    long oBase, int oDiv, long oSA, long oSB, long oSC,
    int K, int addTo, int relu)
{
  __shared__ __hip_bfloat16 As[128 * 64];
  __shared__ __hip_bfloat16 Bs[128 * 64];
  const int tid = threadIdx.x;
  const int rT = blockIdx.y * 128, nT = blockIdx.x * 128;
  const int wave = tid >> 6, lane = tid & 63;
  const int wr = wave >> 1, wc = wave & 1;
  const int lrow = lane & 15, lkg = lane >> 4;

  long asrc[4], bsrc[4];
  const int sc8 = ((lane & 7) ^ (lane >> 3)) * 8;
#pragma unroll
  for (int i = 0; i < 4; ++i) {
    const int chunk = wave * 4 + i;
    const int row = chunk * 8 + (lane >> 3);
    const int gr = rT + row;
    asrc[i] = aBase + (long)(gr / aDiv) * aSA + (long)(gr % aDiv) * aSB + sc8;
    bsrc[i] = (long)(nT + row) * ldw + sc8;
  }

  f32x4 acc[4][4];
#pragma unroll
  for (int i = 0; i < 4; ++i)
#pragma unroll
    for (int j = 0; j < 4; ++j) acc[i][j] = (f32x4){0.f, 0.f, 0.f, 0.f};

  for (int k0 = 0; k0 < K; k0 += 64) {
#pragma unroll
    for (int i = 0; i < 4; ++i) {
      const int chunk = wave * 4 + i;
      GLL16(A + asrc[i] + k0, &As[chunk * 512]);
      GLL16(W + bsrc[i] + k0, &Bs[chunk * 512]);
    }
    __syncthreads();
#pragma unroll
    for (int ks = 0; ks < 2; ++ks) {
      short8 af[4], bfv[4];
#pragma unroll
      for (int f = 0; f < 4; ++f) {
        const int Ra = wr * 64 + f * 16 + lrow;
        af[f] = *(const short8*)&As[Ra * 64 + (((ks * 4 + lkg) ^ (Ra & 7)) * 8)];
        const int Rb = wc * 64 + f * 16 + lrow;
        bfv[f] = *(const short8*)&Bs[Rb * 64 + (((ks * 4 + lkg) ^ (Rb & 7)) * 8)];
      }
#pragma unroll
      for (int fm = 0; fm < 4; ++fm)
#pragma unroll
        for (int fn = 0; fn < 4; ++fn)
          acc[fm][fn] = __builtin_amdgcn_mfma_f32_16x16x32_bf16(af[fm], bfv[fn], acc[fm][fn], 0, 0, 0);
    }
    __syncthreads();
  }

  float bias_v[4];
#pragma unroll
  for (int fn = 0; fn < 4; ++fn)
    bias_v[fn] = bias ? bias[nT + wc * 64 + fn * 16 + lrow] : 0.f;

#pragma unroll
  for (int fm = 0; fm < 4; ++fm) {
#pragma unroll
    for (int r = 0; r < 4; ++r) {
      const int grow = rT + wr * 64 + fm * 16 + lkg * 4 + r;
      const long obase_r = oBase + (long)(grow / oDiv) * oSA + (long)(grow % oDiv) * oSB;
#pragma unroll
      for (int fn = 0; fn < 4; ++fn) {
        const int gcol = nT + wc * 64 + fn * 16 + lrow;
        float v = acc[fm][fn][r] + bias_v[fn];
        if (relu) v = fmaxf(v, 0.f);
        const long o = obase_r + (long)gcol * oSC;
        if (outF) { if (addTo) v += outF[o]; outF[o] = v; }
        else {
          if (addTo) v += __bfloat162float(outB[o]);
          outB[o] = __float2bfloat16(v);
        }
      }
    }
  }
}

// ===================== fp32-input MFMA GEMM (feat only) =====================
__global__ __launch_bounds__(256) void gemm_mfma(
    const float* __restrict__ A, long aBase, int aDiv, long aSA, long aSB,
    const float* __restrict__ W, int ldw,
    const float* __restrict__ bias,
    const float* __restrict__ extra, int extraDiv,
    __hip_bfloat16* __restrict__ outB,
    long oBase, int oDiv, long oSA, long oSB,
    int N, int K)
{
  __shared__ short As[2][128][40];
  __shared__ short Bs[2][128][40];
  const int tid = threadIdx.x;
  const int rT = blockIdx.y * 128, nT = blockIdx.x * 128;
  const int wave = tid >> 6, lane = tid & 63;
  const int wr = wave >> 1, wc = wave & 1;
  const int lrow = lane & 15, lkg = lane >> 4;
  const int srow = tid >> 1, shf = tid & 1;

  const long arow = aBase + (long)((rT + srow) / aDiv) * aSA + (long)((rT + srow) % aDiv) * aSB + shf * 16;
  const long brow = (long)(nT + srow) * ldw + shf * 16;

  f32x4 acc[4][4];
#pragma unroll
  for (int i = 0; i < 4; ++i)
#pragma unroll
    for (int j = 0; j < 4; ++j) acc[i][j] = (f32x4){0.f, 0.f, 0.f, 0.f};

  float4 ra[4], rb[4];
#define LOADT(K0) do { \
    const float* _pa = A + arow + (K0); \
    ra[0] = *(const float4*)(_pa); ra[1] = *(const float4*)(_pa + 4); \
    ra[2] = *(const float4*)(_pa + 8); ra[3] = *(const float4*)(_pa + 12); \
    const float* _pb = W + brow + (K0); \
    rb[0] = *(const float4*)(_pb); rb[1] = *(const float4*)(_pb + 4); \
    rb[2] = *(const float4*)(_pb + 8); rb[3] = *(const float4*)(_pb + 12); \
  } while (0)

#define CVST(DST, X, Y) do { \
    short8 _v; \
    _v[0] = f2bs((X).x); _v[1] = f2bs((X).y); _v[2] = f2bs((X).z); _v[3] = f2bs((X).w); \
    _v[4] = f2bs((Y).x); _v[5] = f2bs((Y).y); _v[6] = f2bs((Y).z); _v[7] = f2bs((Y).w); \
    *(short8*)(DST) = _v; \
  } while (0)

#define STAGE(BUF) do { \
    CVST(&As[BUF][srow][shf * 16],     ra[0], ra[1]); \
    CVST(&As[BUF][srow][shf * 16 + 8], ra[2], ra[3]); \
    CVST(&Bs[BUF][srow][shf * 16],     rb[0], rb[1]); \
    CVST(&Bs[BUF][srow][shf * 16 + 8], rb[2], rb[3]); \
  } while (0)

  LOADT(0);
  STAGE(0);
  __syncthreads();

  int cur = 0;
  for (int k0 = 0; k0 < K; k0 += 32) {
    const bool nlast = (k0 + 32 < K);
    if (nlast) LOADT(k0 + 32);
    short8 af[4], bfv[4];
#pragma unroll
    for (int f = 0; f < 4; ++f)
      af[f] = *(const short8*)&As[cur][wr * 64 + f * 16 + lrow][lkg * 8];
#pragma unroll
    for (int f = 0; f < 4; ++f)
      bfv[f] = *(const short8*)&Bs[cur][wc * 64 + f * 16 + lrow][lkg * 8];
#pragma unroll
    for (int fm = 0; fm < 4; ++fm)
#pragma unroll
      for (int fn = 0; fn < 4; ++fn)
        acc[fm][fn] = __builtin_amdgcn_mfma_f32_16x16x32_bf16(af[fm], bfv[fn], acc[fm][fn], 0, 0, 0);
    if (nlast) STAGE(cur ^ 1);
    __syncthreads();
    cur ^= 1;
  }

  float bias_v[4];
#pragma unroll
  for (int fn = 0; fn < 4; ++fn)
    bias_v[fn] = bias ? bias[nT + wc * 64 + fn * 16 + lrow] : 0.f;

#pragma unroll
  for (int fm = 0; fm < 4; ++fm) {
#pragma unroll
    for (int r = 0; r < 4; ++r) {
      const int grow = rT + wr * 64 + fm * 16 + lkg * 4 + r;
      const long obase_r = oBase + (long)(grow / oDiv) * oSA + (long)(grow % oDiv) * oSB;
      const long exrow = (long)(grow / extraDiv) * N;
#pragma unroll
      for (int fn = 0; fn < 4; ++fn) {
        const int gcol = nT + wc * 64 + fn * 16 + lrow;
        float v = acc[fm][fn][r] + bias_v[fn];
        if (extra) v += extra[exrow + gcol];
        outB[obase_r + gcol] = __float2bfloat16(v);
      }
    }
  }
#undef LOADT
#undef CVST
#undef STAGE
}

// ===================== MFMA attention (per (head, chunk-local b) block) =====================
__global__ __launch_bounds__(256) void attn_kernel(
    const __hip_bfloat16* __restrict__ qkv, __hip_bfloat16* __restrict__ outY, int b0)
{
  __shared__ __align__(16) char arena[101632];
  unsigned short* Qs = (unsigned short*)arena;            // [112][72]
  unsigned short* Ks = Qs + 8064;                         // [112][72]
  unsigned short* Vt = Ks + 8064;                         // [64][136]
  float* S = (float*)(arena + 49664);                     // [112][116]
  unsigned short* Sb = (unsigned short*)arena;            // [112][136] overlays Qs/Ks
  __shared__ float rs_s[112];

  const int h = blockIdx.x, bl = blockIdx.y, tid = threadIdx.x;
  const unsigned short* q16 = (const unsigned short*)qkv;

  for (int idx = tid; idx < 6400; idx += 256) {
    int v = idx >> 6, d = idx & 63;
    long base = ((long)(v * 256 + bl)) * 1536 + h * 64 + d;
    Qs[v * 72 + d] = q16[base];
    Ks[v * 72 + d] = q16[base + 512];
    Vt[d * 136 + v] = q16[base + 1024];
  }
  for (int idx = tid; idx < 12 * 64; idx += 256) {
    int r = 100 + (idx >> 6), c = idx & 63;
    Qs[r * 72 + c] = 0; Ks[r * 72 + c] = 0;
  }
  for (int idx = tid; idx < 64 * 36; idx += 256) {
    int d = idx / 36, c = 100 + idx % 36;
    Vt[d * 136 + c] = 0;
  }
  __syncthreads();

  const int wave = tid >> 6, lane = tid & 63;
  const int lrow = lane & 15, lkg = lane >> 4;

  for (int tt = wave; tt < 49; tt += 4) {
    const int tm = tt / 7, tn = tt % 7;
    f32x4 a = (f32x4){0.f, 0.f, 0.f, 0.f};
#pragma unroll
    for (int ks = 0; ks < 2; ++ks) {
      short8 af = *(const short8*)&Qs[(tm * 16 + lrow) * 72 + ks * 32 + lkg * 8];
      short8 bf = *(const short8*)&Ks[(tn * 16 + lrow) * 72 + ks * 32 + lkg * 8];
      a = __builtin_amdgcn_mfma_f32_16x16x32_bf16(af, bf, a, 0, 0, 0);
    }
#pragma unroll
    for (int r = 0; r < 4; ++r)
      S[(tm * 16 + lkg * 4 + r) * 116 + tn * 16 + lrow] = a[r] * 0.125f;
  }
  __syncthreads();

  {
    unsigned* p = (unsigned*)Sb;
    for (int idx = tid; idx < 7616; idx += 256) p[idx] = 0;
  }
  __syncthreads();

  if (tid < 200) {
    const int r = tid >> 1, hf = tid & 1;
    const float* srow = S + r * 116 + hf * 50;
    float m = -3.0e38f;
    for (int c = 0; c < 50; ++c) m = fmaxf(m, srow[c]);
    m = fmaxf(m, __shfl_xor(m, 1, 64));
    float s = 0.f;
    for (int c = 0; c < 50; ++c) {
      float e = __expf(srow[c] - m);
      Sb[r * 136 + hf * 50 + c] = (unsigned short)f2bs(e);
      s += e;
    }
    s += __shfl_xor(s, 1, 64);
    if (hf == 0) rs_s[r] = 1.f / s;
  }
  __syncthreads();

  for (int tt = wave; tt < 28; tt += 4) {
    const int tm = tt >> 2, tn = tt & 3;
    f32x4 a = (f32x4){0.f, 0.f, 0.f, 0.f};
#pragma unroll
    for (int kc = 0; kc < 4; ++kc) {
      short8 af = *(const short8*)&Sb[(tm * 16 + lrow) * 136 + kc * 32 + lkg * 8];
      short8 bf = *(const short8*)&Vt[(tn * 16 + lrow) * 136 + kc * 32 + lkg * 8];
      a = __builtin_amdgcn_mfma_f32_16x16x32_bf16(af, bf, a, 0, 0, 0);
    }
#pragma unroll
    for (int r = 0; r < 4; ++r) {
      const int m = tm * 16 + lkg * 4 + r;
      if (m < 100) {
        const int n = tn * 16 + lrow;
        outY[((long)(m * 512 + b0 + bl)) * 512 + h * 64 + n] = __float2bfloat16(a[r] * rs_s[m]);
      }
    }
  }
}

// ===================== layernorm (bf16 in-place) =====================
__global__ __launch_bounds__(256) void ln_kernel(__hip_bfloat16* __restrict__ X,
    const float* __restrict__ g, const float* __restrict__ b)
{
  const int row = blockIdx.x * 4 + (threadIdx.x >> 6);
  const int lane = threadIdx.x & 63;
  unsigned short* x = (unsigned short*)X + (long)row * 512 + lane * 8;
  uint4 raw = *(const uint4*)x;
  float v[8];
  v[0] = blo(raw.x); v[1] = bhi(raw.x); v[2] = blo(raw.y); v[3] = bhi(raw.y);
  v[4] = blo(raw.z); v[5] = bhi(raw.z); v[6] = blo(raw.w); v[7] = bhi(raw.w);
  float s = 0.f, sq = 0.f;
#pragma unroll
  for (int i = 0; i < 8; ++i) { s += v[i]; sq += v[i] * v[i]; }
#pragma unroll
  for (int off = 32; off; off >>= 1) { s += __shfl_xor(s, off, 64); sq += __shfl_xor(sq, off, 64); }
  const float mean = s * (1.f / 512.f);
  const float var = sq * (1.f / 512.f) - mean * mean;
  const float inv = rsqrtf(var + 1e-5f);
  const int c0 = lane * 8;
  short8 outv;
#pragma unroll
  for (int i = 0; i < 8; ++i)
    outv[i] = f2bs((v[i] - mean) * inv * g[c0 + i] + b[c0 + i]);
  *(short8*)x = outv;
}

// ===================== decoder init =====================
__global__ void init_kernel(unsigned long long* sh_units, float* c_g) {
  int t = threadIdx.x;
  sh_units[t] = 0ULL;
  sh_units[256 + t] = 0ULL;
  c_g[t] = 0.f; c_g[256 + t] = 0.f;
}

// ===================== decoder: 512-step attention-LSTM scan =====================
// 16 worker blocks (stride-8 colocation), tagged 8B unit sync, W1b/Whh in registers.
// G now read from NATURAL layout [t*100+v][1024] (26 strided ushort loads, clamped).
#define DEC_NB 16

__global__ __launch_bounds__(256, 1) void decoder_kernel(
    const __hip_bfloat16* __restrict__ Xb,  // [V*Tx, 512] bf16
    const __hip_bfloat16* __restrict__ Pb,  // [512][100][128]
    const __hip_bfloat16* __restrict__ Gb,  // [512*100][1024] natural
    const float* __restrict__ att1_w, const float* __restrict__ att1_b,
    const float* __restrict__ att2_w,
    const float* __restrict__ whh,
    const float* __restrict__ bih, const float* __restrict__ bhh,
    const float* __restrict__ fc1_w, const float* __restrict__ fc1_b,
    const float* __restrict__ fc2_w, const float* __restrict__ fc2_b,
    unsigned long long* sh_units,           // [2][256]
    float* c_g,
    float* __restrict__ out)
{
  if (blockIdx.x & 7) return;
  const int tid = threadIdx.x;
  const int blk = blockIdx.x >> 3;
  const int e0 = blk * 16;

  __shared__ __align__(16) float s_h_s[256];
  __shared__ float w2_s[128], ub_s[128], bsum_s[64];
  __shared__ float u_s[128], sc_s[16];
  __shared__ float a2_s[104];
  __shared__ float red_s[256];
  __shared__ float gates_s[64];
  __shared__ float red4_s[4];
  __shared__ float fcin_s[768];
  __shared__ float fca_s[256];

  if (tid < 128) { w2_s[tid] = att2_w[tid]; ub_s[tid] = att1_b[tid]; }
  if (tid < 64) {
    int jg = jglob_of(e0, tid);
    bsum_s[tid] = bih[jg] + bhh[jg];
  }
  if (tid < 16) sc_s[tid] = 0.f;
  if (tid < 4) a2_s[100 + tid] = 0.f;

  const int pv = tid >> 1, ppart = tid & 1;
  const int pvv = (pv < 100) ? pv : 99;
  const int gjl = tid >> 2, gq = tid & 3;
  const int jgG = jglob_of(e0, gjl);

  unsigned W1R[64];
  {
    const int j = tid >> 1, hf = tid & 1;
    const float* wsrc = att1_w + (long)j * 768 + 512 + hf * 128;
#pragma unroll
    for (int i = 0; i < 64; ++i)
      W1R[i] = (unsigned)(unsigned short)f2bs(wsrc[2 * i]) |
               ((unsigned)(unsigned short)f2bs(wsrc[2 * i + 1]) << 16);
  }
  float WHF[64];
  {
    const float* wsrc = whh + (long)jglob_of(e0, gjl) * 256 + gq * 64;
#pragma unroll
    for (int i = 0; i < 64; ++i) WHF[i] = wsrc[i];
  }

  unsigned PCa[32], PCb[32];
  unsigned short GCa[26], GCb[26];

#define PREFETCH(T1, PCd, GCd) do { \
    const uint4* _pp = (const uint4*)Pb + ((((long)(T1) * 100 + pvv) * 128 + ppart * 64) >> 3); \
    _Pragma("unroll") \
    for (int _i = 0; _i < 8; ++_i) { \
      uint4 _t = _pp[_i]; \
      (PCd)[4*_i] = _t.x; (PCd)[4*_i+1] = _t.y; (PCd)[4*_i+2] = _t.z; (PCd)[4*_i+3] = _t.w; \
    } \
    const unsigned short* _gs = (const unsigned short*)Gb + (long)(T1) * 102400 + jgG; \
    _Pragma("unroll") \
    for (int _i = 0; _i < 26; ++_i) { \
      int _v = gq * 26 + _i; if (_v > 99) _v = 99; \
      (GCd)[_i] = _gs[(long)_v * 1024]; \
    } \
  } while (0)

#define STEP(T, PCc, GCc, PCn, GCn) do { \
    { \
      unsigned long long* _up = &sh_units[((((T) & 1) ^ 1) << 8) + tid]; \
      unsigned long long _v = __hip_atomic_load(_up, __ATOMIC_RELAXED, __HIP_MEMORY_SCOPE_AGENT); \
      while ((unsigned)(_v >> 32) < (unsigned)(T)) { \
        __builtin_amdgcn_s_sleep(1); \
        _v = __hip_atomic_load(_up, __ATOMIC_RELAXED, __HIP_MEMORY_SCOPE_AGENT); \
      } \
      s_h_s[tid] = __uint_as_float((unsigned)_v); \
    } \
    __syncthreads(); \
    if ((T) + 1 < 512) PREFETCH((T) + 1, PCn, GCn); \
    { const int _hf = tid & 1, _j = tid >> 1; \
      const float* _sh = &s_h_s[_hf * 128]; \
      float _a = 0.f; \
      _Pragma("unroll") \
      for (int _i = 0; _i < 64; ++_i) { \
        const unsigned _w = W1R[_i]; \
        const float2 _s2 = *(const float2*)(_sh + 2 * _i); \
        _a += blo(_w) * _s2.x + bhi(_w) * _s2.y; \
      } \
      _a += __shfl_xor(_a, 1, 64); \
      if (_hf == 0) u_s[_j] = _a + ub_s[_j]; \
    } \
    float _hhv; \
    { const float* _sh = &s_h_s[gq * 64]; \
      float _a = 0.f; \
      _Pragma("unroll") \
      for (int _i = 0; _i < 16; ++_i) { \
        const float4 _s4 = *(const float4*)(_sh + 4 * _i); \
        _a += WHF[4*_i] * _s4.x + WHF[4*_i+1] * _s4.y + WHF[4*_i+2] * _s4.z + WHF[4*_i+3] * _s4.w; \
      } \
      _a += __shfl_xor(_a, 1, 64); \
      _a += __shfl_xor(_a, 2, 64); \
      _hhv = _a; \
    } \
    __syncthreads(); \
    { float _val = 0.f; \
      _Pragma("unroll") \
      for (int _jj = 0; _jj < 64; ++_jj) { \
        unsigned _u = (PCc)[_jj >> 1]; \
        float _pf = (_jj & 1) ? bhi(_u) : blo(_u); \
        int _col = ppart * 64 + _jj; \
        _val += tanhf_fast(_pf + u_s[_col]) * w2_s[_col]; \
      } \
      _val += __shfl_xor(_val, 1, 64); \
      if (ppart == 0 && pv < 100) a2_s[pv] = _val; \
    } \
    __syncthreads(); \
    if (tid < 64) { \
      float _x0 = a2_s[tid]; \
      float _x1 = (tid + 64 < 100) ? a2_s[tid + 64] : -3.0e38f; \
      float _m = fmaxf(_x0, _x1); \
      _Pragma("unroll") \
      for (int _o = 32; _o; _o >>= 1) _m = fmaxf(_m, __shfl_xor(_m, _o, 64)); \
      float _e0 = __expf(_x0 - _m); \
      float _e1 = (tid + 64 < 100) ? __expf(_x1 - _m) : 0.f; \
      float _s = _e0 + _e1; \
      _Pragma("unroll") \
      for (int _o = 32; _o; _o >>= 1) _s += __shfl_xor(_s, _o, 64); \
      const float _inv = 1.f / (_s + 1e-15f); \
      a2_s[tid] = _e0 * _inv; \
      if (tid + 64 < 100) a2_s[tid + 64] = _e1 * _inv; \
    } \
    __syncthreads(); \
    { float _p = 0.f; \
      _Pragma("unroll") \
      for (int _i = 0; _i < 26; ++_i) \
        _p += a2_s[gq * 26 + _i] * blo((unsigned)(GCc)[_i]); \
      _p += __shfl_xor(_p, 1, 64); \
      _p += __shfl_xor(_p, 2, 64); \
      if (gq == 0) gates_s[gjl] = _p + _hhv + bsum_s[gjl]; \
    } \
    __syncthreads(); \
    if ((T) < 511) { \
      if (tid < 16) { \
        const float _ig = gates_s[tid], _fg = gates_s[16 + tid]; \
        const float _gg = gates_s[32 + tid], _og = gates_s[48 + tid]; \
        const float _si = 1.f / (1.f + __expf(-_ig)); \
        const float _sf = 1.f / (1.f + __expf(-_fg)); \
        const float _so = 1.f / (1.f + __expf(-_og)); \
        const float _sc = _sf * sc_s[tid] + _si * tanhf(_gg); \
        sc_s[tid] = _sc; \
        const float _sh2 = _so * tanhf(_sc); \
        const unsigned long long _v = \
            ((unsigned long long)(unsigned)((T) + 1) << 32) | (unsigned long long)__float_as_uint(_sh2); \
        __hip_atomic_store(&sh_units[(((T) & 1) << 8) + e0 + tid], _v, \
                           __ATOMIC_RELAXED, __HIP_MEMORY_SCOPE_AGENT); \
      } \
    } else { \
      const int _dl = tid & 31, _vs = tid >> 5; \
      const int _v0 = _vs * 13, _v1 = (_v0 + 13 < 100) ? _v0 + 13 : 100; \
      float _ac = 0.f; \
      for (int _v = _v0; _v < _v1; ++_v) \
        _ac += a2_s[_v] * __bfloat162float(Xb[((long)(_v * 512 + 511)) * 512 + blk * 32 + _dl]); \
      red_s[tid] = _ac; \
      __syncthreads(); \
      if (tid < 32) { \
        float _cc = 0.f; \
        _Pragma("unroll") \
        for (int _s = 0; _s < 8; ++_s) _cc += red_s[_s * 32 + tid]; \
        __hip_atomic_store(&c_g[blk * 32 + tid], _cc, __ATOMIC_RELAXED, __HIP_MEMORY_SCOPE_AGENT); \
      } \
      __syncthreads(); \
      if (tid == 0) \
        __hip_atomic_store(&sh_units[256 + e0], 512ULL << 32, \
                           __ATOMIC_RELEASE, __HIP_MEMORY_SCOPE_AGENT); \
    } \
  } while (0)

  PREFETCH(0, PCa, GCa);
  __syncthreads();

  for (int t2 = 0; t2 < 512; t2 += 2) {
    STEP(t2,     PCa, GCa, PCb, GCb);
    STEP(t2 + 1, PCb, GCb, PCa, GCa);
  }

  if (blk == 0) {
    if (tid < DEC_NB) {
      while ((unsigned)(__hip_atomic_load(&sh_units[256 + tid * 16],
                 __ATOMIC_RELAXED, __HIP_MEMORY_SCOPE_AGENT) >> 32) < 512u)
        __builtin_amdgcn_s_sleep(1);
    }
    __builtin_amdgcn_fence(__ATOMIC_ACQUIRE, "agent");
    __syncthreads();
    fcin_s[tid]       = __hip_atomic_load(&c_g[tid],       __ATOMIC_RELAXED, __HIP_MEMORY_SCOPE_AGENT);
    fcin_s[256 + tid] = __hip_atomic_load(&c_g[256 + tid], __ATOMIC_RELAXED, __HIP_MEMORY_SCOPE_AGENT);
    fcin_s[512 + tid] = s_h_s[tid];
    __syncthreads();
    float acc = fc1_b[tid];
    const float* w = fc1_w + (long)tid * 768;
    for (int k = 0; k < 768; ++k) acc += w[k] * fcin_s[k];
    fca_s[tid] = fmaxf(acc, 0.f);
    __syncthreads();
    if (tid < 128) {
      const int r = tid >> 6, k0 = tid & 63;
      float a = 0.f;
#pragma unroll
      for (int s = 0; s < 4; ++s) a += fc2_w[r * 256 + k0 + s * 64] * fca_s[k0 + s * 64];
#pragma unroll
      for (int off = 32; off; off >>= 1) a += __shfl_xor(a, off, 64);
      if (k0 == 0) red4_s[r] = a + fc2_b[r];
    }
    __syncthreads();
    if (tid == 0) {
      const float l0 = red4_s[0], l1 = red4_s[1];
      const float m = fmaxf(l0, l1);
      const float ls = logf(__expf(l0 - m) + __expf(l1 - m));
      out[0] = l0 - m - ls;
      out[1] = l1 - m - ls;
    }
  }
#undef PREFETCH
#undef STEP
}

// ===================== host launch =====================
extern "C" void kernel_launch(void* const* d_in, const int* in_sizes, int n_in,
                              void* d_out, int out_size, void* d_ws, size_t ws_size,
                              hipStream_t stream) {
  const float* x_data  = (const float*)d_in[0];
  const float* feat_w  = (const float*)d_in[1];
  const float* feat_b  = (const float*)d_in[2];
  const float* in_w    = (const float*)d_in[3];
  const float* in_b    = (const float*)d_in[4];
  const float* out_w   = (const float*)d_in[5];
  const float* out_b   = (const float*)d_in[6];
  const float* ff1_w   = (const float*)d_in[7];
  const float* ff1_b   = (const float*)d_in[8];
  const float* ff2_w   = (const float*)d_in[9];
  const float* ff2_b   = (const float*)d_in[10];
  const float* ln1_g   = (const float*)d_in[11];
  const float* ln1_b   = (const float*)d_in[12];
  const float* ln2_g   = (const float*)d_in[13];
  const float* ln2_b   = (const float*)d_in[14];
  const float* att1_w  = (const float*)d_in[15];
  const float* att1_b  = (const float*)d_in[16];
  const float* att2_w  = (const float*)d_in[17];
  const float* lstm_wih = (const float*)d_in[19];
  const float* lstm_whh = (const float*)d_in[20];
  const float* lstm_bih = (const float*)d_in[21];
  const float* lstm_bhh = (const float*)d_in[22];
  const float* fc1_w   = (const float*)d_in[23];
  const float* fc1_b   = (const float*)d_in[24];
  const float* fc2_w   = (const float*)d_in[25];
  const float* fc2_b   = (const float*)d_in[26];

  // ---- workspace layout (floats), ~198 MB total ----
  float* ws   = (float*)d_ws;
  __hip_bfloat16* Xb = (__hip_bfloat16*)ws;                // [51200,512] bf16 = 13,107,200 f
  float* R2   = ws + 13107200;                             // big region
  __hip_bfloat16* qkvb = (__hip_bfloat16*)R2;              // chunk [25600,1536]
  __hip_bfloat16* ctxb = (__hip_bfloat16*)(R2 + 19660800); // full [51200,512]
  __hip_bfloat16* ffh  = (__hip_bfloat16*)R2;              // chunk [25600,2048] (overlay)
  __hip_bfloat16* PbB  = (__hip_bfloat16*)R2;              // [512][100][128] (overlay)
  __hip_bfloat16* GbB  = (__hip_bfloat16*)(R2 + 3276800);  // [512*100][1024] (overlay)
  __hip_bfloat16* wbp  = (__hip_bfloat16*)(R2 + 32768000); // bf16 weight pool (6,881,280 shorts)
  __hip_bfloat16* in_wb  = wbp;
  __hip_bfloat16* out_wb = wbp + 1572864;
  __hip_bfloat16* ff1_wb = wbp + 2097152;
  __hip_bfloat16* ff2_wb = wbp + 4194304;
  __hip_bfloat16* att1c  = wbp + 6291456;
  __hip_bfloat16* wih_b  = wbp + 6356992;
  float* pe    = R2 + 32768000 + 3440640;
  unsigned long long* sh_units = (unsigned long long*)(pe + 51200);  // [2][256]
  float* c_g   = (float*)(sh_units + 512);

  // fused prologue: all 6 weight converts + PE table in one dispatch
  prep_kernel<<<(6881280 + 51200 + 255) / 256, 256, 0, stream>>>(
      in_w, out_w, ff1_w, ff2_w, att1_w, lstm_wih, wbp, pe);

  // feature map + PE -> Xb (bf16)
  gemm_mfma<<<dim3(4, 400), 256, 0, stream>>>(
      x_data, 0L, 512, 64L, 6400L, feat_w, 64, feat_b, pe, 512,
      Xb, 0L, 1 << 30, 0L, 512L, 512, 64);

  for (int l = 0; l < 2; ++l) {
    for (int c = 0; c < 2; ++c) {
      const long b0 = c * 256;
      gemm_bf16<<<dim3(12, 200), 256, 0, stream>>>(
          Xb, b0 * 512, 256, 262144L, 512L,
          in_wb + (long)l * 786432, 512, in_b + l * 1536,
          nullptr, qkvb, 0L, 1 << 30, 0L, 1536L, 1L, 512, 0, 0);
      attn_kernel<<<dim3(8, 256), 256, 0, stream>>>(qkvb, ctxb, (int)b0);
    }
    gemm_bf16<<<dim3(4, 400), 256, 0, stream>>>(
        ctxb, 0L, 1 << 30, 0L, 512L,
        out_wb + (long)l * 262144, 512, out_b + l * 512,
        nullptr, Xb, 0L, 1 << 30, 0L, 512L, 1L, 512, 1, 0);
    ln_kernel<<<12800, 256, 0, stream>>>(Xb, ln1_g + l * 512, ln1_b + l * 512);
    for (int rc = 0; rc < 2; ++rc) {
      const long r0 = (long)rc * 25600;
      gemm_bf16<<<dim3(16, 200), 256, 0, stream>>>(
          Xb, r0 * 512, 1 << 30, 0L, 512L,
          ff1_wb + (long)l * 1048576, 512, ff1_b + l * 2048,
          nullptr, ffh, 0L, 1 << 30, 0L, 2048L, 1L, 512, 0, 1);
      gemm_bf16<<<dim3(4, 200), 256, 0, stream>>>(
          ffh, 0L, 1 << 30, 0L, 2048L,
          ff2_wb + (long)l * 1048576, 2048, ff2_b + l * 512,
          nullptr, Xb, r0 * 512, 1 << 30, 0L, 512L, 1L, 2048, 1, 0);
    }
    ln_kernel<<<12800, 256, 0, stream>>>(Xb, ln2_g + l * 512, ln2_b + l * 512);
  }

  // P[t*100+v][:] = h[t][v] @ att1_w[:, :512]^T
  gemm_bf16<<<dim3(1, 400), 256, 0, stream>>>(
      Xb, 0L, 100, 512L, 262144L, att1c, 512, nullptr,
      nullptr, PbB, 0L, 1 << 30, 0L, 128L, 1L, 512, 0, 0);
  // G[t*100+v][:] = h[t][v] @ wih^T  (NATURAL layout, coalesced stores)
  gemm_bf16<<<dim3(8, 400), 256, 0, stream>>>(
      Xb, 0L, 100, 512L, 262144L, wih_b, 512, nullptr,
      nullptr, GbB, 0L, 1 << 30, 0L, 1024L, 1L, 512, 0, 0);

  init_kernel<<<1, 256, 0, stream>>>(sh_units, c_g);
  decoder_kernel<<<DEC_NB * 8, 256, 0, stream>>>(
      Xb, PbB, GbB, att1_w, att1_b, att2_w,
      lstm_whh, lstm_bih, lstm_bhh, fc1_w, fc1_b, fc2_w, fc2_b,
      sh_units, c_g, (float*)d_out);
}

// Round 15
// 4656.036 us; speedup vs baseline: 1.1917x; 1.1917x over previous
//
#include <hip/hip_runtime.h>
#include <hip/hip_bf16.h>

// Model dims: Tx=512 V=100 D=64 DM=512 NH=8 DFF=2048 NL=2 H=256 DATT=128 FCH=256 OUT=2

typedef __attribute__((ext_vector_type(8))) short short8;
typedef __attribute__((ext_vector_type(4))) float f32x4;

__device__ __forceinline__ int jglob_of(int e0, int jl) { return ((jl >> 4) << 8) + e0 + (jl & 15); }
__device__ __forceinline__ float blo(unsigned u) { return __uint_as_float(u << 16); }
__device__ __forceinline__ float bhi(unsigned u) { return __uint_as_float(u & 0xffff0000u); }
__device__ __forceinline__ short f2bs(float x) {
  union { __hip_bfloat16 h; short s; } u; u.h = __float2bfloat16(x); return u.s;
}
__device__ __forceinline__ float tanhf_fast(float x) {
  float e = __expf(2.f * x);
  return 1.f - 2.f * __builtin_amdgcn_rcpf(e + 1.f);
}

#define GLL16(GSRC, LDST) \
  __builtin_amdgcn_global_load_lds( \
      (const __attribute__((address_space(1))) unsigned int*)(GSRC), \
      (__attribute__((address_space(3))) unsigned int*)(LDST), 16, 0, 0)

// ===================== fused prologue: 6 weight converts + PE table =====================
__global__ __launch_bounds__(256) void prep_kernel(
    const float* __restrict__ in_w, const float* __restrict__ out_w,
    const float* __restrict__ ff1_w, const float* __restrict__ ff2_w,
    const float* __restrict__ att1_w, const float* __restrict__ wih,
    __hip_bfloat16* __restrict__ dst, float* __restrict__ pe)
{
  int i = blockIdx.x * 256 + threadIdx.x;
  if (i < 6881280) {
    const float* s; long off;
    if (i < 1572864)      { s = in_w;  off = i; }
    else if (i < 2097152) { s = out_w; off = i - 1572864; }
    else if (i < 4194304) { s = ff1_w; off = i - 2097152; }
    else if (i < 6291456) { s = ff2_w; off = i - 4194304; }
    else if (i < 6356992) { int k = i - 6291456; s = att1_w; off = (long)(k >> 9) * 768 + (k & 511); }
    else                  { s = wih;   off = i - 6356992; }
    dst[i] = __float2bfloat16(s[off]);
  } else if (i < 6881280 + 51200) {
    int idx = i - 6881280;
    int v = idx >> 9, n = idx & 511;
    float d = expf(-(float)(n & ~1) * (9.2103403719761836f / 512.0f));
    float ang = (float)v * d;
    pe[idx] = (n & 1) ? cosf(ang) : sinf(ang);
  }
}

// ===================== bf16-input MFMA GEMM (m97-style) =====================
__global__ __launch_bounds__(256) void gemm_bf16(
    const __hip_bfloat16* __restrict__ A, long aBase, int aDiv, long aSA, long aSB,
    const __hip_bfloat16* __restrict__ W, int ldw,
    const float* __restrict__ bias,
    float* __restrict__ outF, __hip_bfloat16* __restrict__ outB,
    long oBase, int oDiv, long oSA, long oSB, long oSC,
    int K, int addTo, int relu)
{
  __shared__ __hip_bfloat16 As[128 * 64];
  __shared__ __hip_bfloat16 Bs[128 * 64];
  const int tid = threadIdx.x;
  const int rT = blockIdx.y * 128, nT = blockIdx.x * 128;
  const int wave = tid >> 6, lane = tid & 63;
  const int wr = wave >> 1, wc = wave & 1;
  const int lrow = lane & 15, lkg = lane >> 4;

  long asrc[4], bsrc[4];
  const int sc8 = ((lane & 7) ^ (lane >> 3)) * 8;
#pragma unroll
  for (int i = 0; i < 4; ++i) {
    const int chunk = wave * 4 + i;
    const int row = chunk * 8 + (lane >> 3);
    const int gr = rT + row;
    asrc[i] = aBase + (long)(gr / aDiv) * aSA + (long)(gr % aDiv) * aSB + sc8;
    bsrc[i] = (long)(nT + row) * ldw + sc8;
  }

  f32x4 acc[4][4];
#pragma unroll
  for (int i = 0; i < 4; ++i)
#pragma unroll
    for (int j = 0; j < 4; ++j) acc[i][j] = (f32x4){0.f, 0.f, 0.f, 0.f};

  for (int k0 = 0; k0 < K; k0 += 64) {
#pragma unroll
    for (int i = 0; i < 4; ++i) {
      const int chunk = wave * 4 + i;
      GLL16(A + asrc[i] + k0, &As[chunk * 512]);
      GLL16(W + bsrc[i] + k0, &Bs[chunk * 512]);
    }
    __syncthreads();
#pragma unroll
    for (int ks = 0; ks < 2; ++ks) {
      short8 af[4], bfv[4];
#pragma unroll
      for (int f = 0; f < 4; ++f) {
        const int Ra = wr * 64 + f * 16 + lrow;
        af[f] = *(const short8*)&As[Ra * 64 + (((ks * 4 + lkg) ^ (Ra & 7)) * 8)];
        const int Rb = wc * 64 + f * 16 + lrow;
        bfv[f] = *(const short8*)&Bs[Rb * 64 + (((ks * 4 + lkg) ^ (Rb & 7)) * 8)];
      }
#pragma unroll
      for (int fm = 0; fm < 4; ++fm)
#pragma unroll
        for (int fn = 0; fn < 4; ++fn)
          acc[fm][fn] = __builtin_amdgcn_mfma_f32_16x16x32_bf16(af[fm], bfv[fn], acc[fm][fn], 0, 0, 0);
    }
    __syncthreads();
  }

  float bias_v[4];
#pragma unroll
  for (int fn = 0; fn < 4; ++fn)
    bias_v[fn] = bias ? bias[nT + wc * 64 + fn * 16 + lrow] : 0.f;

#pragma unroll
  for (int fm = 0; fm < 4; ++fm) {
#pragma unroll
    for (int r = 0; r < 4; ++r) {
      const int grow = rT + wr * 64 + fm * 16 + lkg * 4 + r;
      const long obase_r = oBase + (long)(grow / oDiv) * oSA + (long)(grow % oDiv) * oSB;
#pragma unroll
      for (int fn = 0; fn < 4; ++fn) {
        const int gcol = nT + wc * 64 + fn * 16 + lrow;
        float v = acc[fm][fn][r] + bias_v[fn];
        if (relu) v = fmaxf(v, 0.f);
        const long o = obase_r + (long)gcol * oSC;
        if (outF) { if (addTo) v += outF[o]; outF[o] = v; }
        else {
          if (addTo) v += __bfloat162float(outB[o]);
          outB[o] = __float2bfloat16(v);
        }
      }
    }
  }
}

// ===================== fp32-input MFMA GEMM (feat only) =====================
__global__ __launch_bounds__(256) void gemm_mfma(
    const float* __restrict__ A, long aBase, int aDiv, long aSA, long aSB,
    const float* __restrict__ W, int ldw,
    const float* __restrict__ bias,
    const float* __restrict__ extra, int extraDiv,
    __hip_bfloat16* __restrict__ outB,
    long oBase, int oDiv, long oSA, long oSB,
    int N, int K)
{
  __shared__ short As[2][128][40];
  __shared__ short Bs[2][128][40];
  const int tid = threadIdx.x;
  const int rT = blockIdx.y * 128, nT = blockIdx.x * 128;
  const int wave = tid >> 6, lane = tid & 63;
  const int wr = wave >> 1, wc = wave & 1;
  const int lrow = lane & 15, lkg = lane >> 4;
  const int srow = tid >> 1, shf = tid & 1;

  const long arow = aBase + (long)((rT + srow) / aDiv) * aSA + (long)((rT + srow) % aDiv) * aSB + shf * 16;
  const long brow = (long)(nT + srow) * ldw + shf * 16;

  f32x4 acc[4][4];
#pragma unroll
  for (int i = 0; i < 4; ++i)
#pragma unroll
    for (int j = 0; j < 4; ++j) acc[i][j] = (f32x4){0.f, 0.f, 0.f, 0.f};

  float4 ra[4], rb[4];
#define LOADT(K0) do { \
    const float* _pa = A + arow + (K0); \
    ra[0] = *(const float4*)(_pa); ra[1] = *(const float4*)(_pa + 4); \
    ra[2] = *(const float4*)(_pa + 8); ra[3] = *(const float4*)(_pa + 12); \
    const float* _pb = W + brow + (K0); \
    rb[0] = *(const float4*)(_pb); rb[1] = *(const float4*)(_pb + 4); \
    rb[2] = *(const float4*)(_pb + 8); rb[3] = *(const float4*)(_pb + 12); \
  } while (0)

#define CVST(DST, X, Y) do { \
    short8 _v; \
    _v[0] = f2bs((X).x); _v[1] = f2bs((X).y); _v[2] = f2bs((X).z); _v[3] = f2bs((X).w); \
    _v[4] = f2bs((Y).x); _v[5] = f2bs((Y).y); _v[6] = f2bs((Y).z); _v[7] = f2bs((Y).w); \
    *(short8*)(DST) = _v; \
  } while (0)

#define STAGE(BUF) do { \
    CVST(&As[BUF][srow][shf * 16],     ra[0], ra[1]); \
    CVST(&As[BUF][srow][shf * 16 + 8], ra[2], ra[3]); \
    CVST(&Bs[BUF][srow][shf * 16],     rb[0], rb[1]); \
    CVST(&Bs[BUF][srow][shf * 16 + 8], rb[2], rb[3]); \
  } while (0)

  LOADT(0);
  STAGE(0);
  __syncthreads();

  int cur = 0;
  for (int k0 = 0; k0 < K; k0 += 32) {
    const bool nlast = (k0 + 32 < K);
    if (nlast) LOADT(k0 + 32);
    short8 af[4], bfv[4];
#pragma unroll
    for (int f = 0; f < 4; ++f)
      af[f] = *(const short8*)&As[cur][wr * 64 + f * 16 + lrow][lkg * 8];
#pragma unroll
    for (int f = 0; f < 4; ++f)
      bfv[f] = *(const short8*)&Bs[cur][wc * 64 + f * 16 + lrow][lkg * 8];
#pragma unroll
    for (int fm = 0; fm < 4; ++fm)
#pragma unroll
      for (int fn = 0; fn < 4; ++fn)
        acc[fm][fn] = __builtin_amdgcn_mfma_f32_16x16x32_bf16(af[fm], bfv[fn], acc[fm][fn], 0, 0, 0);
    if (nlast) STAGE(cur ^ 1);
    __syncthreads();
    cur ^= 1;
  }

  float bias_v[4];
#pragma unroll
  for (int fn = 0; fn < 4; ++fn)
    bias_v[fn] = bias ? bias[nT + wc * 64 + fn * 16 + lrow] : 0.f;

#pragma unroll
  for (int fm = 0; fm < 4; ++fm) {
#pragma unroll
    for (int r = 0; r < 4; ++r) {
      const int grow = rT + wr * 64 + fm * 16 + lkg * 4 + r;
      const long obase_r = oBase + (long)(grow / oDiv) * oSA + (long)(grow % oDiv) * oSB;
      const long exrow = (long)(grow / extraDiv) * N;
#pragma unroll
      for (int fn = 0; fn < 4; ++fn) {
        const int gcol = nT + wc * 64 + fn * 16 + lrow;
        float v = acc[fm][fn][r] + bias_v[fn];
        if (extra) v += extra[exrow + gcol];
        outB[obase_r + gcol] = __float2bfloat16(v);
      }
    }
  }
#undef LOADT
#undef CVST
#undef STAGE
}

// ===================== MFMA attention (per (head, chunk-local b) block) =====================
__global__ __launch_bounds__(256) void attn_kernel(
    const __hip_bfloat16* __restrict__ qkv, __hip_bfloat16* __restrict__ outY, int b0)
{
  __shared__ __align__(16) char arena[101632];
  unsigned short* Qs = (unsigned short*)arena;            // [112][72]
  unsigned short* Ks = Qs + 8064;                         // [112][72]
  unsigned short* Vt = Ks + 8064;                         // [64][136]
  float* S = (float*)(arena + 49664);                     // [112][116]
  unsigned short* Sb = (unsigned short*)arena;            // [112][136] overlays Qs/Ks
  __shared__ float rs_s[112];

  const int h = blockIdx.x, bl = blockIdx.y, tid = threadIdx.x;
  const unsigned short* q16 = (const unsigned short*)qkv;

  for (int idx = tid; idx < 6400; idx += 256) {
    int v = idx >> 6, d = idx & 63;
    long base = ((long)(v * 256 + bl)) * 1536 + h * 64 + d;
    Qs[v * 72 + d] = q16[base];
    Ks[v * 72 + d] = q16[base + 512];
    Vt[d * 136 + v] = q16[base + 1024];
  }
  for (int idx = tid; idx < 12 * 64; idx += 256) {
    int r = 100 + (idx >> 6), c = idx & 63;
    Qs[r * 72 + c] = 0; Ks[r * 72 + c] = 0;
  }
  for (int idx = tid; idx < 64 * 36; idx += 256) {
    int d = idx / 36, c = 100 + idx % 36;
    Vt[d * 136 + c] = 0;
  }
  __syncthreads();

  const int wave = tid >> 6, lane = tid & 63;
  const int lrow = lane & 15, lkg = lane >> 4;

  for (int tt = wave; tt < 49; tt += 4) {
    const int tm = tt / 7, tn = tt % 7;
    f32x4 a = (f32x4){0.f, 0.f, 0.f, 0.f};
#pragma unroll
    for (int ks = 0; ks < 2; ++ks) {
      short8 af = *(const short8*)&Qs[(tm * 16 + lrow) * 72 + ks * 32 + lkg * 8];
      short8 bf = *(const short8*)&Ks[(tn * 16 + lrow) * 72 + ks * 32 + lkg * 8];
      a = __builtin_amdgcn_mfma_f32_16x16x32_bf16(af, bf, a, 0, 0, 0);
    }
#pragma unroll
    for (int r = 0; r < 4; ++r)
      S[(tm * 16 + lkg * 4 + r) * 116 + tn * 16 + lrow] = a[r] * 0.125f;
  }
  __syncthreads();

  {
    unsigned* p = (unsigned*)Sb;
    for (int idx = tid; idx < 7616; idx += 256) p[idx] = 0;
  }
  __syncthreads();

  if (tid < 200) {
    const int r = tid >> 1, hf = tid & 1;
    const float* srow = S + r * 116 + hf * 50;
    float m = -3.0e38f;
    for (int c = 0; c < 50; ++c) m = fmaxf(m, srow[c]);
    m = fmaxf(m, __shfl_xor(m, 1, 64));
    float s = 0.f;
    for (int c = 0; c < 50; ++c) {
      float e = __expf(srow[c] - m);
      Sb[r * 136 + hf * 50 + c] = (unsigned short)f2bs(e);
      s += e;
    }
    s += __shfl_xor(s, 1, 64);
    if (hf == 0) rs_s[r] = 1.f / s;
  }
  __syncthreads();

  for (int tt = wave; tt < 28; tt += 4) {
    const int tm = tt >> 2, tn = tt & 3;
    f32x4 a = (f32x4){0.f, 0.f, 0.f, 0.f};
#pragma unroll
    for (int kc = 0; kc < 4; ++kc) {
      short8 af = *(const short8*)&Sb[(tm * 16 + lrow) * 136 + kc * 32 + lkg * 8];
      short8 bf = *(const short8*)&Vt[(tn * 16 + lrow) * 136 + kc * 32 + lkg * 8];
      a = __builtin_amdgcn_mfma_f32_16x16x32_bf16(af, bf, a, 0, 0, 0);
    }
#pragma unroll
    for (int r = 0; r < 4; ++r) {
      const int m = tm * 16 + lkg * 4 + r;
      if (m < 100) {
        const int n = tn * 16 + lrow;
        outY[((long)(m * 512 + b0 + bl)) * 512 + h * 64 + n] = __float2bfloat16(a[r] * rs_s[m]);
      }
    }
  }
}

// ===================== layernorm (bf16 in-place) =====================
__global__ __launch_bounds__(256) void ln_kernel(__hip_bfloat16* __restrict__ X,
    const float* __restrict__ g, const float* __restrict__ b)
{
  const int row = blockIdx.x * 4 + (threadIdx.x >> 6);
  const int lane = threadIdx.x & 63;
  unsigned short* x = (unsigned short*)X + (long)row * 512 + lane * 8;
  uint4 raw = *(const uint4*)x;
  float v[8];
  v[0] = blo(raw.x); v[1] = bhi(raw.x); v[2] = blo(raw.y); v[3] = bhi(raw.y);
  v[4] = blo(raw.z); v[5] = bhi(raw.z); v[6] = blo(raw.w); v[7] = bhi(raw.w);
  float s = 0.f, sq = 0.f;
#pragma unroll
  for (int i = 0; i < 8; ++i) { s += v[i]; sq += v[i] * v[i]; }
#pragma unroll
  for (int off = 32; off; off >>= 1) { s += __shfl_xor(s, off, 64); sq += __shfl_xor(sq, off, 64); }
  const float mean = s * (1.f / 512.f);
  const float var = sq * (1.f / 512.f) - mean * mean;
  const float inv = rsqrtf(var + 1e-5f);
  const int c0 = lane * 8;
  short8 outv;
#pragma unroll
  for (int i = 0; i < 8; ++i)
    outv[i] = f2bs((v[i] - mean) * inv * g[c0 + i] + b[c0 + i]);
  *(short8*)x = outv;
}

// ===================== decoder init =====================
__global__ void init_kernel(unsigned long long* sh_units, float* c_g) {
  int t = threadIdx.x;
  sh_units[t] = 0ULL;
  sh_units[256 + t] = 0ULL;
  c_g[t] = 0.f; c_g[256 + t] = 0.f;
}

// ===================== decoder: 512-step attention-LSTM scan =====================
// 16 worker blocks (stride-8 colocation), tagged 8B unit sync, W1b/Whh in registers.
// G in [t][j][v] transposed layout (13 contiguous dwords/thread — round-13 proven).
#define DEC_NB 16

__global__ __launch_bounds__(256, 1) void decoder_kernel(
    const __hip_bfloat16* __restrict__ Xb,  // [V*Tx, 512] bf16
    const __hip_bfloat16* __restrict__ Pb,  // [512][100][128]
    const __hip_bfloat16* __restrict__ Gb,  // [512][1024][100]
    const float* __restrict__ att1_w, const float* __restrict__ att1_b,
    const float* __restrict__ att2_w,
    const float* __restrict__ whh,
    const float* __restrict__ bih, const float* __restrict__ bhh,
    const float* __restrict__ fc1_w, const float* __restrict__ fc1_b,
    const float* __restrict__ fc2_w, const float* __restrict__ fc2_b,
    unsigned long long* sh_units,           // [2][256]
    float* c_g,
    float* __restrict__ out)
{
  if (blockIdx.x & 7) return;
  const int tid = threadIdx.x;
  const int blk = blockIdx.x >> 3;
  const int e0 = blk * 16;

  __shared__ __align__(16) float s_h_s[256];
  __shared__ float w2_s[128], ub_s[128], bsum_s[64];
  __shared__ float u_s[128], sc_s[16];
  __shared__ float a2_s[104];
  __shared__ float red_s[256];
  __shared__ float gates_s[64];
  __shared__ float red4_s[4];
  __shared__ float fcin_s[768];
  __shared__ float fca_s[256];

  if (tid < 128) { w2_s[tid] = att2_w[tid]; ub_s[tid] = att1_b[tid]; }
  if (tid < 64) {
    int jg = jglob_of(e0, tid);
    bsum_s[tid] = bih[jg] + bhh[jg];
  }
  if (tid < 16) sc_s[tid] = 0.f;
  if (tid < 4) a2_s[100 + tid] = 0.f;

  const int pv = tid >> 1, ppart = tid & 1;
  const int pvv = (pv < 100) ? pv : 99;
  const int gjl = tid >> 2, gq = tid & 3;
  const long gRowOff = (long)jglob_of(e0, gjl) * 100 + gq * 26;

  unsigned W1R[64];
  {
    const int j = tid >> 1, hf = tid & 1;
    const float* wsrc = att1_w + (long)j * 768 + 512 + hf * 128;
#pragma unroll
    for (int i = 0; i < 64; ++i)
      W1R[i] = (unsigned)(unsigned short)f2bs(wsrc[2 * i]) |
               ((unsigned)(unsigned short)f2bs(wsrc[2 * i + 1]) << 16);
  }
  float WHF[64];
  {
    const float* wsrc = whh + (long)jglob_of(e0, gjl) * 256 + gq * 64;
#pragma unroll
    for (int i = 0; i < 64; ++i) WHF[i] = wsrc[i];
  }

  unsigned PCa[32], PCb[32];
  unsigned GCa[13], GCb[13];

#define PREFETCH(T1, PCd, GCd) do { \
    const uint4* _pp = (const uint4*)Pb + ((((long)(T1) * 100 + pvv) * 128 + ppart * 64) >> 3); \
    _Pragma("unroll") \
    for (int _i = 0; _i < 8; ++_i) { \
      uint4 _t = _pp[_i]; \
      (PCd)[4*_i] = _t.x; (PCd)[4*_i+1] = _t.y; (PCd)[4*_i+2] = _t.z; (PCd)[4*_i+3] = _t.w; \
    } \
    const unsigned* _gp = (const unsigned*)(Gb + (long)(T1) * 102400 + gRowOff); \
    _Pragma("unroll") \
    for (int _i = 0; _i < 13; ++_i) (GCd)[_i] = _gp[_i]; \
  } while (0)

#define STEP(T, PCc, GCc, PCn, GCn) do { \
    { \
      unsigned long long* _up = &sh_units[((((T) & 1) ^ 1) << 8) + tid]; \
      unsigned long long _v = __hip_atomic_load(_up, __ATOMIC_RELAXED, __HIP_MEMORY_SCOPE_AGENT); \
      while ((unsigned)(_v >> 32) < (unsigned)(T)) { \
        __builtin_amdgcn_s_sleep(1); \
        _v = __hip_atomic_load(_up, __ATOMIC_RELAXED, __HIP_MEMORY_SCOPE_AGENT); \
      } \
      s_h_s[tid] = __uint_as_float((unsigned)_v); \
    } \
    __syncthreads(); \
    if ((T) + 1 < 512) PREFETCH((T) + 1, PCn, GCn); \
    { const int _hf = tid & 1, _j = tid >> 1; \
      const float* _sh = &s_h_s[_hf * 128]; \
      float _a = 0.f; \
      _Pragma("unroll") \
      for (int _i = 0; _i < 64; ++_i) { \
        const unsigned _w = W1R[_i]; \
        const float2 _s2 = *(const float2*)(_sh + 2 * _i); \
        _a += blo(_w) * _s2.x + bhi(_w) * _s2.y; \
      } \
      _a += __shfl_xor(_a, 1, 64); \
      if (_hf == 0) u_s[_j] = _a + ub_s[_j]; \
    } \
    float _hhv; \
    { const float* _sh = &s_h_s[gq * 64]; \
      float _a = 0.f; \
      _Pragma("unroll") \
      for (int _i = 0; _i < 16; ++_i) { \
        const float4 _s4 = *(const float4*)(_sh + 4 * _i); \
        _a += WHF[4*_i] * _s4.x + WHF[4*_i+1] * _s4.y + WHF[4*_i+2] * _s4.z + WHF[4*_i+3] * _s4.w; \
      } \
      _a += __shfl_xor(_a, 1, 64); \
      _a += __shfl_xor(_a, 2, 64); \
      _hhv = _a; \
    } \
    __syncthreads(); \
    { float _val = 0.f; \
      _Pragma("unroll") \
      for (int _jj = 0; _jj < 64; ++_jj) { \
        unsigned _u = (PCc)[_jj >> 1]; \
        float _pf = (_jj & 1) ? bhi(_u) : blo(_u); \
        int _col = ppart * 64 + _jj; \
        _val += tanhf_fast(_pf + u_s[_col]) * w2_s[_col]; \
      } \
      _val += __shfl_xor(_val, 1, 64); \
      if (ppart == 0 && pv < 100) a2_s[pv] = _val; \
    } \
    __syncthreads(); \
    if (tid < 64) { \
      float _x0 = a2_s[tid]; \
      float _x1 = (tid + 64 < 100) ? a2_s[tid + 64] : -3.0e38f; \
      float _m = fmaxf(_x0, _x1); \
      _Pragma("unroll") \
      for (int _o = 32; _o; _o >>= 1) _m = fmaxf(_m, __shfl_xor(_m, _o, 64)); \
      float _e0 = __expf(_x0 - _m); \
      float _e1 = (tid + 64 < 100) ? __expf(_x1 - _m) : 0.f; \
      float _s = _e0 + _e1; \
      _Pragma("unroll") \
      for (int _o = 32; _o; _o >>= 1) _s += __shfl_xor(_s, _o, 64); \
      const float _inv = 1.f / (_s + 1e-15f); \
      a2_s[tid] = _e0 * _inv; \
      if (tid + 64 < 100) a2_s[tid + 64] = _e1 * _inv; \
    } \
    __syncthreads(); \
    { float _p = 0.f; \
      _Pragma("unroll") \
      for (int _i = 0; _i < 13; ++_i) { \
        unsigned _u = (GCc)[_i]; \
        _p += a2_s[gq * 26 + 2 * _i] * blo(_u); \
        _p += a2_s[gq * 26 + 2 * _i + 1] * bhi(_u); \
      } \
      _p += __shfl_xor(_p, 1, 64); \
      _p += __shfl_xor(_p, 2, 64); \
      if (gq == 0) gates_s[gjl] = _p + _hhv + bsum_s[gjl]; \
    } \
    __syncthreads(); \
    if ((T) < 511) { \
      if (tid < 16) { \
        const float _ig = gates_s[tid], _fg = gates_s[16 + tid]; \
        const float _gg = gates_s[32 + tid], _og = gates_s[48 + tid]; \
        const float _si = 1.f / (1.f + __expf(-_ig)); \
        const float _sf = 1.f / (1.f + __expf(-_fg)); \
        const float _so = 1.f / (1.f + __expf(-_og)); \
        const float _sc = _sf * sc_s[tid] + _si * tanhf(_gg); \
        sc_s[tid] = _sc; \
        const float _sh2 = _so * tanhf(_sc); \
        const unsigned long long _v = \
            ((unsigned long long)(unsigned)((T) + 1) << 32) | (unsigned long long)__float_as_uint(_sh2); \
        __hip_atomic_store(&sh_units[(((T) & 1) << 8) + e0 + tid], _v, \
                           __ATOMIC_RELAXED, __HIP_MEMORY_SCOPE_AGENT); \
      } \
    } else { \
      const int _dl = tid & 31, _vs = tid >> 5; \
      const int _v0 = _vs * 13, _v1 = (_v0 + 13 < 100) ? _v0 + 13 : 100; \
      float _ac = 0.f; \
      for (int _v = _v0; _v < _v1; ++_v) \
        _ac += a2_s[_v] * __bfloat162float(Xb[((long)(_v * 512 + 511)) * 512 + blk * 32 + _dl]); \
      red_s[tid] = _ac; \
      __syncthreads(); \
      if (tid < 32) { \
        float _cc = 0.f; \
        _Pragma("unroll") \
        for (int _s = 0; _s < 8; ++_s) _cc += red_s[_s * 32 + tid]; \
        __hip_atomic_store(&c_g[blk * 32 + tid], _cc, __ATOMIC_RELAXED, __HIP_MEMORY_SCOPE_AGENT); \
      } \
      __syncthreads(); \
      if (tid == 0) \
        __hip_atomic_store(&sh_units[256 + e0], 512ULL << 32, \
                           __ATOMIC_RELEASE, __HIP_MEMORY_SCOPE_AGENT); \
    } \
  } while (0)

  PREFETCH(0, PCa, GCa);
  __syncthreads();

  for (int t2 = 0; t2 < 512; t2 += 2) {
    STEP(t2,     PCa, GCa, PCb, GCb);
    STEP(t2 + 1, PCb, GCb, PCa, GCa);
  }

  if (blk == 0) {
    if (tid < DEC_NB) {
      while ((unsigned)(__hip_atomic_load(&sh_units[256 + tid * 16],
                 __ATOMIC_RELAXED, __HIP_MEMORY_SCOPE_AGENT) >> 32) < 512u)
        __builtin_amdgcn_s_sleep(1);
    }
    __builtin_amdgcn_fence(__ATOMIC_ACQUIRE, "agent");
    __syncthreads();
    fcin_s[tid]       = __hip_atomic_load(&c_g[tid],       __ATOMIC_RELAXED, __HIP_MEMORY_SCOPE_AGENT);
    fcin_s[256 + tid] = __hip_atomic_load(&c_g[256 + tid], __ATOMIC_RELAXED, __HIP_MEMORY_SCOPE_AGENT);
    fcin_s[512 + tid] = s_h_s[tid];
    __syncthreads();
    float acc = fc1_b[tid];
    const float* w = fc1_w + (long)tid * 768;
    for (int k = 0; k < 768; ++k) acc += w[k] * fcin_s[k];
    fca_s[tid] = fmaxf(acc, 0.f);
    __syncthreads();
    if (tid < 128) {
      const int r = tid >> 6, k0 = tid & 63;
      float a = 0.f;
#pragma unroll
      for (int s = 0; s < 4; ++s) a += fc2_w[r * 256 + k0 + s * 64] * fca_s[k0 + s * 64];
#pragma unroll
      for (int off = 32; off; off >>= 1) a += __shfl_xor(a, off, 64);
      if (k0 == 0) red4_s[r] = a + fc2_b[r];
    }
    __syncthreads();
    if (tid == 0) {
      const float l0 = red4_s[0], l1 = red4_s[1];
      const float m = fmaxf(l0, l1);
      const float ls = logf(__expf(l0 - m) + __expf(l1 - m));
      out[0] = l0 - m - ls;
      out[1] = l1 - m - ls;
    }
  }
#undef PREFETCH
#undef STEP
}

// ===================== host launch =====================
extern "C" void kernel_launch(void* const* d_in, const int* in_sizes, int n_in,
                              void* d_out, int out_size, void* d_ws, size_t ws_size,
                              hipStream_t stream) {
  const float* x_data  = (const float*)d_in[0];
  const float* feat_w  = (const float*)d_in[1];
  const float* feat_b  = (const float*)d_in[2];
  const float* in_w    = (const float*)d_in[3];
  const float* in_b    = (const float*)d_in[4];
  const float* out_w   = (const float*)d_in[5];
  const float* out_b   = (const float*)d_in[6];
  const float* ff1_w   = (const float*)d_in[7];
  const float* ff1_b   = (const float*)d_in[8];
  const float* ff2_w   = (const float*)d_in[9];
  const float* ff2_b   = (const float*)d_in[10];
  const float* ln1_g   = (const float*)d_in[11];
  const float* ln1_b   = (const float*)d_in[12];
  const float* ln2_g   = (const float*)d_in[13];
  const float* ln2_b   = (const float*)d_in[14];
  const float* att1_w  = (const float*)d_in[15];
  const float* att1_b  = (const float*)d_in[16];
  const float* att2_w  = (const float*)d_in[17];
  const float* lstm_wih = (const float*)d_in[19];
  const float* lstm_whh = (const float*)d_in[20];
  const float* lstm_bih = (const float*)d_in[21];
  const float* lstm_bhh = (const float*)d_in[22];
  const float* fc1_w   = (const float*)d_in[23];
  const float* fc1_b   = (const float*)d_in[24];
  const float* fc2_w   = (const float*)d_in[25];
  const float* fc2_b   = (const float*)d_in[26];

  // ---- workspace layout (floats), ~198 MB total ----
  float* ws   = (float*)d_ws;
  __hip_bfloat16* Xb = (__hip_bfloat16*)ws;                // [51200,512] bf16
  float* R2   = ws + 13107200;                             // big region
  __hip_bfloat16* qkvb = (__hip_bfloat16*)R2;              // chunk [25600,1536]
  __hip_bfloat16* ctxb = (__hip_bfloat16*)(R2 + 19660800); // full [51200,512]
  __hip_bfloat16* ffh  = (__hip_bfloat16*)R2;              // chunk [25600,2048] (overlay)
  __hip_bfloat16* PbB  = (__hip_bfloat16*)R2;              // [512][100][128] (overlay)
  __hip_bfloat16* GbB  = (__hip_bfloat16*)(R2 + 3276800);  // [512][1024][100] (overlay)
  __hip_bfloat16* wbp  = (__hip_bfloat16*)(R2 + 32768000); // bf16 weight pool
  __hip_bfloat16* in_wb  = wbp;
  __hip_bfloat16* out_wb = wbp + 1572864;
  __hip_bfloat16* ff1_wb = wbp + 2097152;
  __hip_bfloat16* ff2_wb = wbp + 4194304;
  __hip_bfloat16* att1c  = wbp + 6291456;
  __hip_bfloat16* wih_b  = wbp + 6356992;
  float* pe    = R2 + 32768000 + 3440640;
  unsigned long long* sh_units = (unsigned long long*)(pe + 51200);  // [2][256]
  float* c_g   = (float*)(sh_units + 512);

  prep_kernel<<<(6881280 + 51200 + 255) / 256, 256, 0, stream>>>(
      in_w, out_w, ff1_w, ff2_w, att1_w, lstm_wih, wbp, pe);

  gemm_mfma<<<dim3(4, 400), 256, 0, stream>>>(
      x_data, 0L, 512, 64L, 6400L, feat_w, 64, feat_b, pe, 512,
      Xb, 0L, 1 << 30, 0L, 512L, 512, 64);

  for (int l = 0; l < 2; ++l) {
    for (int c = 0; c < 2; ++c) {
      const long b0 = c * 256;
      gemm_bf16<<<dim3(12, 200), 256, 0, stream>>>(
          Xb, b0 * 512, 256, 262144L, 512L,
          in_wb + (long)l * 786432, 512, in_b + l * 1536,
          nullptr, qkvb, 0L, 1 << 30, 0L, 1536L, 1L, 512, 0, 0);
      attn_kernel<<<dim3(8, 256), 256, 0, stream>>>(qkvb, ctxb, (int)b0);
    }
    gemm_bf16<<<dim3(4, 400), 256, 0, stream>>>(
        ctxb, 0L, 1 << 30, 0L, 512L,
        out_wb + (long)l * 262144, 512, out_b + l * 512,
        nullptr, Xb, 0L, 1 << 30, 0L, 512L, 1L, 512, 1, 0);
    ln_kernel<<<12800, 256, 0, stream>>>(Xb, ln1_g + l * 512, ln1_b + l * 512);
    for (int rc = 0; rc < 2; ++rc) {
      const long r0 = (long)rc * 25600;
      gemm_bf16<<<dim3(16, 200), 256, 0, stream>>>(
          Xb, r0 * 512, 1 << 30, 0L, 512L,
          ff1_wb + (long)l * 1048576, 512, ff1_b + l * 2048,
          nullptr, ffh, 0L, 1 << 30, 0L, 2048L, 1L, 512, 0, 1);
      gemm_bf16<<<dim3(4, 200), 256, 0, stream>>>(
          ffh, 0L, 1 << 30, 0L, 2048L,
          ff2_wb + (long)l * 1048576, 2048, ff2_b + l * 512,
          nullptr, Xb, r0 * 512, 1 << 30, 0L, 512L, 1L, 2048, 1, 0);
    }
    ln_kernel<<<12800, 256, 0, stream>>>(Xb, ln2_g + l * 512, ln2_b + l * 512);
  }

  // P[t*100+v][:] = h[t][v] @ att1_w[:, :512]^T
  gemm_bf16<<<dim3(1, 400), 256, 0, stream>>>(
      Xb, 0L, 100, 512L, 262144L, att1c, 512, nullptr,
      nullptr, PbB, 0L, 1 << 30, 0L, 128L, 1L, 512, 0, 0);
  // G[t][j][v] = (h[t][v] @ wih^T)[j]  (transposed store via oSC=100 — round-13 proven)
  gemm_bf16<<<dim3(8, 400), 256, 0, stream>>>(
      Xb, 0L, 100, 512L, 262144L, wih_b, 512, nullptr,
      nullptr, GbB, 0L, 100, 102400L, 1L, 100L, 512, 0, 0);

  init_kernel<<<1, 256, 0, stream>>>(sh_units, c_g);
  decoder_kernel<<<DEC_NB * 8, 256, 0, stream>>>(
      Xb, PbB, GbB, att1_w, att1_b, att2_w,
      lstm_whh, lstm_bih, lstm_bhh, fc1_w, fc1_b, fc2_w, fc2_b,
      sh_units, c_g, (float*)d_out);
}